// Round 8
// baseline (12574.943 us; speedup 1.0000x reference)
//
#include <hip/hip_runtime.h>
#include <math.h>

// Problem sizes
#define T_N 900
#define H_N 400
#define C_N 73
#define F_N 240
#define B_N 32
#define G4H 1600          // 4*H
#define BT  (B_N * T_N)   // 28800

// ---- recurrence config ----
#define RG   8     // batch rows per row-group
#define NGRP 4     // row groups  (4*8 = 32 = B)
#define NBLK 25    // hidden-unit blocks per lstm (25*16 = 400 = H)
#define HSZ  16    // hidden units per block
#define KCH  100   // h k-chunk per wave (4 waves * 100 = 400 = H)
#define KXC  60    // x k-chunk per wave (4 waves * 60  = 240 = F)
#define HELEM (RG * H_N)           // 3200 h elements per domain

// ---- workspace layout (floats); total ~23.25M floats = 93.0 MB ----
#define HS_OFF  0ULL
#define HS_SZ   ((size_t)BT * H_N)             // 11,520,000 per lstm
#define HB_OFF  (2 * HS_SZ)                    // tagged h broadcast (u64)
#define HB_U64  ((size_t)2 * NGRP * 2 * HELEM) // [2][4 grp][2 parity][3200]

typedef unsigned long long u64;

__device__ __forceinline__ float sigf(float x) {
    return 1.0f / (1.0f + expf(-x));   // precise exp: 900-step drift safety
}

// ============================================================
// Persistent masked-LSTM recurrence, FULL T=900, both LSTMs,
// x@Wx fused (no xz GEMM, no chunking).
// grid = 200 blocks: [2 lstm][4 grp][25 unit-blocks], 256 thr.
// Wh slice (100 VGPR) + Wx slice (60 VGPR) per thread.
// h exchanged via 8B tagged relaxed agent-scope atomics {tag,h},
// parity (t&1) buffers; BATCHED re-poll; wave-local h staging
// (no pre-FMA barrier).  x-partial for t+1 computed after the
// publish of t+1 (hides in the store-to-visibility window).
//
// Parity-overwrite safety: block W writes tag t+2 into an element
// only after W's step-(t+1) poll saw tag t+1 on ALL elements incl.
// those owned by any reader R; R publishes t+1 only after the
// __syncthreads that follows all of R's staging reads of the tag-t
// buffer -> every tag-t read completes before any t+2 overwrite.
// ============================================================
__global__ __launch_bounds__(256, 1)
void lstm_rec(const float* __restrict__ Wh_c, const float* __restrict__ Wh_l,
              const float* __restrict__ Wx_c, const float* __restrict__ Wx_l,
              const float* __restrict__ b_c,  const float* __restrict__ b_l,
              const int* __restrict__ seq_len,
              const float* __restrict__ x,
              float* __restrict__ hs_all,
              u64* __restrict__ hb64)
{
    __shared__ float hsm[RG][404];        // staged h(t)   (wave k-chunks)
    __shared__ float xsm[RG][244];        // staged x(t+1) (wave k-chunks)
    __shared__ float part[4][RG][64];     // per-wave partial z sums

    const int bid = blockIdx.x;
    const int L   = bid / (NGRP * NBLK);
    const int rem = bid % (NGRP * NBLK);
    const int g   = rem / NBLK;
    const int nb  = rem % NBLK;
    const int tid  = threadIdx.x;
    const int wave = tid >> 6;
    const int lane = tid & 63;

    const float* Wh = L ? Wh_l : Wh_c;
    const float* Wx = L ? Wx_l : Wx_c;
    const float* bv = L ? b_l  : b_c;
    float* hs = hs_all + (size_t)L * HS_SZ;
    u64* hb = hb64 + (size_t)(L * NGRP + g) * (2 * HELEM);

    float* hsm_f = &hsm[0][0];
    float* xsm_f = &xsm[0][0];

    // ---- load Wh + Wx slices into registers (once) ----
    const int gate = lane >> 4;            // 0..3  (Keras gate order i,f,g,o)
    const int jj_l = lane & 15;
    const int gcol = gate * H_N + nb * HSZ + jj_l;   // column in [0,1600)
    float wreg[KCH];
#pragma unroll
    for (int kk = 0; kk < KCH; ++kk)
        wreg[kk] = Wh[(size_t)(wave * KCH + kk) * G4H + gcol];
    float wxreg[KXC];
#pragma unroll
    for (int kk = 0; kk < KXC; ++kk)
        wxreg[kk] = Wx[(size_t)(wave * KXC + kk) * G4H + gcol];

    // ---- row-group max length (uniform across the 25-block domain) ----
    int maxlen = 0;
#pragma unroll
    for (int r = 0; r < RG; ++r) {
        int v = seq_len[g * RG + r];
        maxlen = v > maxlen ? v : maxlen;
    }

    // ---- poll-element mapping: wave handles h[r][k], k in wave's 100-chunk.
    //      flat j = lane + 64*i (i<13, j<800): r=j/100, k=100*wave + j%100
    int ea[13], lofs[13];
#pragma unroll
    for (int i = 0; i < 13; ++i) {
        const int j = lane + (i << 6);
        const int r = j / 100;
        const int k = wave * KCH + (j - r * 100);
        ea[i]   = (j < 800) ? (r * H_N + k) : -1;
        lofs[i] = r * 404 + k;
    }
    // ---- x stage mapping: j2 = lane + 64*i (i<8, j2<480): r=j2/60
    int xgofs[8], xlofs[8];
#pragma unroll
    for (int i = 0; i < 8; ++i) {
        const int j2 = lane + (i << 6);
        const int r = j2 / 60;
        const int kx = wave * KXC + (j2 - r * 60);
        xgofs[i] = (j2 < 480) ? (int)((g * RG + r) * (T_N * F_N) + kx) : -1;
        xlofs[i] = r * 244 + kx;
    }

    // ---- gate-phase constants (tid < 128): (row rr, unit jjs) ----
    const int rr  = tid >> 4;
    const int jjs = tid & 15;
    const int bidx = g * RG + rr;
    const int uu   = nb * HSZ + jjs;
    const int mylen = (tid < 128) ? seq_len[bidx] : 0;
    float bq[4] = {0.f, 0.f, 0.f, 0.f};
    if (tid < 128) {
#pragma unroll
        for (int q = 0; q < 4; ++q) bq[q] = bv[q * H_N + uu];
    }
    float cst = 0.0f, hst = 0.0f;

    // ---- prologue: stage x(0) + x-partial(0) ----
    float accx[RG];
#pragma unroll
    for (int r = 0; r < RG; ++r) accx[r] = 0.0f;
    if (maxlen > 0) {
        float xr[8];
#pragma unroll
        for (int i = 0; i < 8; ++i)
            if (xgofs[i] >= 0) xr[i] = x[xgofs[i]];        // t=0
#pragma unroll
        for (int i = 0; i < 8; ++i)
            if (xgofs[i] >= 0) xsm_f[xlofs[i]] = xr[i];
#pragma unroll
        for (int k4 = 0; k4 < KXC / 4; ++k4) {
            const float w0 = wxreg[k4 * 4 + 0];
            const float w1 = wxreg[k4 * 4 + 1];
            const float w2 = wxreg[k4 * 4 + 2];
            const float w3 = wxreg[k4 * 4 + 3];
#pragma unroll
            for (int r = 0; r < RG; ++r) {
                const float4 xv = *(const float4*)&xsm[r][wave * KXC + k4 * 4];
                accx[r] = fmaf(w0, xv.x, accx[r]);
                accx[r] = fmaf(w1, xv.y, accx[r]);
                accx[r] = fmaf(w2, xv.z, accx[r]);
                accx[r] = fmaf(w3, xv.w, accx[r]);
            }
        }
    }

    for (int t = 0; t < maxlen; ++t) {
        const int tn = t + 1;
        const bool ldx = (tn < maxlen);

        // 1. issue x loads for t+1 (complete during the h poll)
        float xr[8];
        if (ldx) {
#pragma unroll
            for (int i = 0; i < 8; ++i)
                if (xgofs[i] >= 0) xr[i] = x[xgofs[i] + tn * F_N];
        }

        // 2. BATCHED poll of h(t): re-issue ALL pending loads per round
        {
            const u64* src = hb + (size_t)(t & 1) * HELEM;
            u64 v[13];
            bool rdy[13];
#pragma unroll
            for (int i = 0; i < 13; ++i) rdy[i] = (ea[i] < 0);
            bool pend = true;
            while (pend) {
                pend = false;
#pragma unroll
                for (int i = 0; i < 13; ++i)
                    if (!rdy[i])
                        v[i] = __hip_atomic_load(src + ea[i], __ATOMIC_RELAXED,
                                                 __HIP_MEMORY_SCOPE_AGENT);
#pragma unroll
                for (int i = 0; i < 13; ++i) {
                    if (!rdy[i]) {
                        if ((unsigned)(v[i] >> 32) == (unsigned)t) {
                            hsm_f[lofs[i]] = __uint_as_float((unsigned)v[i]);
                            rdy[i] = true;
                        } else {
                            pend = true;
                        }
                    }
                }
            }
        }

        // 3. stage x(t+1) into LDS (loads from step 1 are done by now)
        if (ldx) {
#pragma unroll
            for (int i = 0; i < 8; ++i)
                if (xgofs[i] >= 0) xsm_f[xlofs[i]] = xr[i];
        }

        // 4. h-FMA (wave-local chunk; no barrier needed before this)
        float acc[RG];
#pragma unroll
        for (int r = 0; r < RG; ++r) acc[r] = accx[r];
#pragma unroll
        for (int k4 = 0; k4 < KCH / 4; ++k4) {
            const float w0 = wreg[k4 * 4 + 0];
            const float w1 = wreg[k4 * 4 + 1];
            const float w2 = wreg[k4 * 4 + 2];
            const float w3 = wreg[k4 * 4 + 3];
#pragma unroll
            for (int r = 0; r < RG; ++r) {
                const float4 hv = *(const float4*)&hsm[r][wave * KCH + k4 * 4];
                acc[r] = fmaf(w0, hv.x, acc[r]);
                acc[r] = fmaf(w1, hv.y, acc[r]);
                acc[r] = fmaf(w2, hv.z, acc[r]);
                acc[r] = fmaf(w3, hv.w, acc[r]);
            }
        }
#pragma unroll
        for (int r = 0; r < RG; ++r) part[wave][r][lane] = acc[r];
        __syncthreads();

        // 5. gate math + state update + publish (tid < 128)
        if (tid < 128) {
            float z[4];
#pragma unroll
            for (int q = 0; q < 4; ++q) {
                const int c = q * HSZ + jjs;
                z[q] = part[0][rr][c] + part[1][rr][c] +
                       part[2][rr][c] + part[3][rr][c] + bq[q];
            }
            const float iv = sigf(z[0]);
            const float fv = sigf(z[1]);
            const float gv = tanhf(z[2]);
            const float ov = sigf(z[3]);
            if (t < mylen) {                  // Keras mask: carry if masked
                cst = fv * cst + iv * gv;
                hst = ov * tanhf(cst);
            }
            // publish h(t+1) FIRST (critical path), then hs store
            const u64 pack = ((u64)(unsigned)tn << 32) |
                             (u64)__float_as_uint(hst);
            __hip_atomic_store(hb + (size_t)(tn & 1) * HELEM + (rr * H_N + uu),
                               pack, __ATOMIC_RELAXED,
                               __HIP_MEMORY_SCOPE_AGENT);
            hs[((size_t)bidx * T_N + t) * H_N + uu] = hst;
        }
        __syncthreads();   // protect part[] overwrite next iteration

        // 6. x-partial for t+1 — runs while publishes propagate the fabric
        if (ldx) {
#pragma unroll
            for (int r = 0; r < RG; ++r) accx[r] = 0.0f;
#pragma unroll
            for (int k4 = 0; k4 < KXC / 4; ++k4) {
                const float w0 = wxreg[k4 * 4 + 0];
                const float w1 = wxreg[k4 * 4 + 1];
                const float w2 = wxreg[k4 * 4 + 2];
                const float w3 = wxreg[k4 * 4 + 3];
#pragma unroll
                for (int r = 0; r < RG; ++r) {
                    const float4 xv = *(const float4*)&xsm[r][wave * KXC + k4 * 4];
                    accx[r] = fmaf(w0, xv.x, accx[r]);
                    accx[r] = fmaf(w1, xv.y, accx[r]);
                    accx[r] = fmaf(w2, xv.z, accx[r]);
                    accx[r] = fmaf(w3, xv.w, accx[r]);
                }
            }
        }
    }

    // ---- tail: t >= maxlen — h frozen, just emit hs rows; Keras mask
    //      semantics: frozen h equals h(len-1) for each row ----
    if (tid < 128) {
        for (int t = maxlen; t < T_N; ++t)
            hs[((size_t)bidx * T_N + t) * H_N + uu] = hst;
    }
}

// ============================================================
// Dense heads: logits = hs @ Wd + bd over all 28800 rows.
// BM=128, N=73(->80), BK=16.
// ============================================================
__global__ __launch_bounds__(256)
void dense_proj(const float* __restrict__ hs_all,
                const float* __restrict__ Wd_c, const float* __restrict__ bd_c,
                const float* __restrict__ Wd_l, const float* __restrict__ bd_l,
                float* __restrict__ out)
{
    const int L = blockIdx.y;
    const float* hs = hs_all + (size_t)L * HS_SZ;
    const float* Wd = L ? Wd_l : Wd_c;
    const float* bd = L ? bd_l : bd_c;
    float* o = out + (size_t)L * ((size_t)BT * C_N);

    const int m0 = blockIdx.x * 128;
    const int tid = threadIdx.x;

    __shared__ float As[16][132];
    __shared__ float Bs[16][80];

    const int r  = tid >> 1;          // 0..127
    const int kq = (tid & 1) * 8;     // 0/8
    const float* ap_base = hs + (size_t)(m0 + r) * H_N + kq;

    const int ty = tid >> 4, tx = tid & 15;
    float acc[8][5];
#pragma unroll
    for (int i = 0; i < 8; ++i)
#pragma unroll
        for (int j = 0; j < 5; ++j) acc[i][j] = 0.0f;

    for (int k0 = 0; k0 < H_N; k0 += 16) {
        float4 a0 = *(const float4*)(ap_base + k0);
        float4 a1 = *(const float4*)(ap_base + k0 + 4);
        As[kq + 0][r] = a0.x; As[kq + 1][r] = a0.y;
        As[kq + 2][r] = a0.z; As[kq + 3][r] = a0.w;
        As[kq + 4][r] = a1.x; As[kq + 5][r] = a1.y;
        As[kq + 6][r] = a1.z; As[kq + 7][r] = a1.w;
        for (int i = tid; i < 16 * 80; i += 256) {
            int kk = i / 80, c = i - kk * 80;
            Bs[kk][c] = (c < C_N) ? Wd[(size_t)(k0 + kk) * C_N + c] : 0.0f;
        }
        __syncthreads();
#pragma unroll
        for (int kk = 0; kk < 16; ++kk) {
            float a[8], bb[5];
            *(float4*)&a[0] = *(const float4*)&As[kk][ty * 8];
            *(float4*)&a[4] = *(const float4*)&As[kk][ty * 8 + 4];
#pragma unroll
            for (int j = 0; j < 5; ++j) bb[j] = Bs[kk][tx * 5 + j];
#pragma unroll
            for (int i = 0; i < 8; ++i)
#pragma unroll
                for (int j = 0; j < 5; ++j)
                    acc[i][j] = fmaf(a[i], bb[j], acc[i][j]);
        }
        __syncthreads();
    }

#pragma unroll
    for (int i = 0; i < 8; ++i) {
        const int m = m0 + ty * 8 + i;
#pragma unroll
        for (int j = 0; j < 5; ++j) {
            const int c = tx * 5 + j;
            if (c < C_N)
                o[(size_t)m * C_N + c] = acc[i][j] + bd[c];
        }
    }
}

// ============================================================
// max |a - b|  -> scalar (atomicMax on int bits, vals >= 0)
// ============================================================
__global__ void maxdiff_k(const float* __restrict__ a,
                          const float* __restrict__ b,
                          int* __restrict__ outbits, size_t n)
{
    size_t i0 = (size_t)blockIdx.x * blockDim.x + threadIdx.x;
    float m = 0.0f;
    for (size_t i = i0; i < n; i += (size_t)gridDim.x * blockDim.x) {
        float d = fabsf(a[i] - b[i]);
        m = d > m ? d : m;
    }
#pragma unroll
    for (int off = 32; off > 0; off >>= 1) {
        float o = __shfl_down(m, off, 64);
        m = o > m ? o : m;
    }
    __shared__ float sm[4];
    if ((threadIdx.x & 63) == 0) sm[threadIdx.x >> 6] = m;
    __syncthreads();
    if (threadIdx.x == 0) {
        float mm = sm[0];
#pragma unroll
        for (int w = 1; w < 4; ++w) mm = sm[w] > mm ? sm[w] : mm;
        atomicMax(outbits, __float_as_int(mm));
    }
}

// ============================================================
extern "C" void kernel_launch(void* const* d_in, const int* in_sizes, int n_in,
                              void* d_out, int out_size, void* d_ws, size_t ws_size,
                              hipStream_t stream)
{
    const float* x    = (const float*)d_in[0];
    const int*   slen = (const int*)  d_in[1];
    const float* Wx_c = (const float*)d_in[2];
    const float* Wh_c = (const float*)d_in[3];
    const float* b_c  = (const float*)d_in[4];
    const float* Wx_l = (const float*)d_in[5];
    const float* Wh_l = (const float*)d_in[6];
    const float* b_l  = (const float*)d_in[7];
    const float* Wd_c = (const float*)d_in[8];
    const float* bd_c = (const float*)d_in[9];
    const float* Wd_l = (const float*)d_in[10];
    const float* bd_l = (const float*)d_in[11];

    float* ws    = (float*)d_ws;
    float* hsbuf = ws + HS_OFF;
    u64*   hb64  = (u64*)(ws + HB_OFF);
    float* out   = (float*)d_out;

    // zero tagged h-broadcast buffers ({tag=0, h=0} == t=0 initial state)
    // + output scalar slot
    hipMemsetAsync(hb64, 0, HB_U64 * sizeof(u64), stream);
    hipMemsetAsync(out + 2 * (size_t)BT * C_N, 0, sizeof(float), stream);

    // 1) full recurrence, both LSTMs, x@Wx fused (single dispatch)
    lstm_rec<<<dim3(2 * NGRP * NBLK), dim3(256), 0, stream>>>(
        Wh_c, Wh_l, Wx_c, Wx_l, b_c, b_l, slen, x, hsbuf, hb64);

    // 2) dense heads (all rows at once)
    {
        dim3 grid(BT / 128, 2);   // (225, 2)
        dense_proj<<<grid, 256, 0, stream>>>(hsbuf, Wd_c, bd_c, Wd_l, bd_l,
                                             out);
    }

    // 3) max |logits_c - logits_l|
    maxdiff_k<<<dim3(1024), 256, 0, stream>>>(
        out, out + (size_t)BT * C_N, (int*)(out + 2 * (size_t)BT * C_N),
        (size_t)BT * C_N);
}

// Round 10
// 11792.481 us; speedup vs baseline: 1.0664x; 1.0664x over previous
//
#include <hip/hip_runtime.h>
#include <math.h>

// Problem sizes
#define T_N 900
#define H_N 400
#define C_N 73
#define F_N 240
#define B_N 32
#define G4H 1600          // 4*H
#define BT  (B_N * T_N)   // 28800

// ---- recurrence config ----
#define RG   8     // batch rows per row-group
#define NGRP 4     // row groups  (4*8 = 32 = B)
#define NBLK 25    // hidden-unit blocks per lstm (25*16 = 400 = H)
#define HSZ  16    // hidden units per block
#define KCH  100   // h k-chunk per wave (4 waves * 100 = 400 = H)
#define KXC  60    // x k-chunk per wave (4 waves * 60  = 240 = F)
#define PAIRS 1600 // u64 h-pairs per parity per domain (3200 floats / 2)

// ---- workspace layout (floats); total ~23.09M floats = 92.4 MB ----
#define HS_OFF  0ULL
#define HS_SZ   ((size_t)BT * H_N)             // 11,520,000 per lstm
#define HB_OFF  (2 * HS_SZ)                    // paired h broadcast (u64)
#define HB_U64  ((size_t)2 * NGRP * 2 * PAIRS) // [2][4 grp][2 parity][1600]
#define CNT_OFF (HB_OFF + 2 * HB_U64)          // per-domain counters (ints)
#define CNT_I   (8 * 16)                       // 8 domains, own cacheline

typedef unsigned long long u64;

__device__ __forceinline__ float sigf(float x) {
    return 1.0f / (1.0f + expf(-x));   // precise exp: 900-step drift safety
}

// ============================================================
// Persistent masked-LSTM recurrence, FULL T=900, both LSTMs,
// x@Wx fused.  grid = 200 blocks: [2 lstm][4 grp][25 unit-blk].
// Wh slice (100 VGPR) + Wx slice (60 VGPR) per thread.
//
// Sync protocol (NO fences, NO data re-poll):
//   publisher: pack 2 h into one 8B relaxed agent-scope atomic
//   store (served at the coherence point) -> __syncthreads
//   (vmcnt(0) drain acknowledges the stores) -> tid0 relaxed
//   atomicAdd on the domain counter.
//   reader: tid0 spins on cnt >= 25*t (s_sleep-throttled),
//   __syncthreads, then each thread issues its 7 u64 atomic loads
//   ONCE - freshness guaranteed (stores were acknowledged before
//   the add the reader observed; atomic loads are served at the
//   same coherence point).
// Parity overwrite safety: a block's step-t loads drain at the
// phase-5 barrier before its step-t add; any block reaches step
// t+1 publishing (same parity as t) only after cnt >= 25*(t+1),
// i.e. after ALL blocks' step-t reads completed.
// ============================================================
__global__ __launch_bounds__(256, 1)
void lstm_rec(const float* __restrict__ Wh_c, const float* __restrict__ Wh_l,
              const float* __restrict__ Wx_c, const float* __restrict__ Wx_l,
              const float* __restrict__ b_c,  const float* __restrict__ b_l,
              const int* __restrict__ seq_len,
              const float* __restrict__ x,
              float* __restrict__ hs_all,
              u64* __restrict__ hb64,
              int* __restrict__ cnt)
{
    __shared__ float hsm[RG][404];        // staged h(t)   (wave k-chunks)
    __shared__ float xsm[RG][244];        // staged x(t+1) (wave k-chunks)
    __shared__ float part[4][RG][64];     // per-wave partial z sums

    const int bid = blockIdx.x;
    const int L   = bid / (NGRP * NBLK);
    const int rem = bid % (NGRP * NBLK);
    const int g   = rem / NBLK;
    const int nb  = rem % NBLK;
    const int tid  = threadIdx.x;
    const int wave = tid >> 6;
    const int lane = tid & 63;

    const float* Wh = L ? Wh_l : Wh_c;
    const float* Wx = L ? Wx_l : Wx_c;
    const float* bv = L ? b_l  : b_c;
    float* hs = hs_all + (size_t)L * HS_SZ;
    u64* hb = hb64 + (size_t)(L * NGRP + g) * (2 * PAIRS);
    int* mycnt = cnt + (L * NGRP + g) * 16;   // own cacheline

    float* xsm_f = &xsm[0][0];

    // ---- load Wh + Wx slices into registers (once) ----
    const int gate = lane >> 4;            // 0..3  (Keras gate order i,f,g,o)
    const int jj_l = lane & 15;
    const int gcol = gate * H_N + nb * HSZ + jj_l;   // column in [0,1600)
    float wreg[KCH];
#pragma unroll
    for (int kk = 0; kk < KCH; ++kk)
        wreg[kk] = Wh[(size_t)(wave * KCH + kk) * G4H + gcol];
    float wxreg[KXC];
#pragma unroll
    for (int kk = 0; kk < KXC; ++kk)
        wxreg[kk] = Wx[(size_t)(wave * KXC + kk) * G4H + gcol];

    // ---- row-group max length (uniform across the 25-block domain) ----
    int maxlen = 0;
#pragma unroll
    for (int r = 0; r < RG; ++r) {
        int v = seq_len[g * RG + r];
        maxlen = v > maxlen ? v : maxlen;
    }

    // ---- x stage mapping: j2 = lane + 64*i (i<8, j2<480): r=j2/60
    int xgofs[8], xlofs[8];
#pragma unroll
    for (int i = 0; i < 8; ++i) {
        const int j2 = lane + (i << 6);
        const int r = j2 / 60;
        const int kx = wave * KXC + (j2 - r * 60);
        xgofs[i] = (j2 < 480) ? (int)((g * RG + r) * (T_N * F_N) + kx) : -1;
        xlofs[i] = r * 244 + kx;
    }

    // ---- gate-phase constants (tid < 128): (row rr, unit jjs) ----
    const int rr  = tid >> 4;
    const int jjs = tid & 15;
    const int bidx = g * RG + rr;
    const int uu   = nb * HSZ + jjs;
    const int mylen = (tid < 128) ? seq_len[bidx] : 0;
    float bq[4] = {0.f, 0.f, 0.f, 0.f};
    if (tid < 128) {
#pragma unroll
        for (int q = 0; q < 4; ++q) bq[q] = bv[q * H_N + uu];
    }
    float cst = 0.0f, hst = 0.0f;

    // ---- prologue: stage x(0) + x-partial(0) ----
    float accx[RG];
#pragma unroll
    for (int r = 0; r < RG; ++r) accx[r] = 0.0f;
    if (maxlen > 0) {
        float xr[8];
#pragma unroll
        for (int i = 0; i < 8; ++i)
            if (xgofs[i] >= 0) xr[i] = x[xgofs[i]];        // t=0
#pragma unroll
        for (int i = 0; i < 8; ++i)
            if (xgofs[i] >= 0) xsm_f[xlofs[i]] = xr[i];
#pragma unroll
        for (int k4 = 0; k4 < KXC / 4; ++k4) {
            const float w0 = wxreg[k4 * 4 + 0];
            const float w1 = wxreg[k4 * 4 + 1];
            const float w2 = wxreg[k4 * 4 + 2];
            const float w3 = wxreg[k4 * 4 + 3];
#pragma unroll
            for (int r = 0; r < RG; ++r) {
                const float4 xv = *(const float4*)&xsm[r][wave * KXC + k4 * 4];
                accx[r] = fmaf(w0, xv.x, accx[r]);
                accx[r] = fmaf(w1, xv.y, accx[r]);
                accx[r] = fmaf(w2, xv.z, accx[r]);
                accx[r] = fmaf(w3, xv.w, accx[r]);
            }
        }
    }

    for (int t = 0; t < maxlen; ++t) {
        const int tn = t + 1;
        const bool ldx = (tn < maxlen);

        // 1. issue x loads for t+1 (complete during the counter wait)
        float xr[8];
        if (ldx) {
#pragma unroll
            for (int i = 0; i < 8; ++i)
                if (xgofs[i] >= 0) xr[i] = x[xgofs[i] + tn * F_N];
        }

        // 2. counter gate for h(t)  (t=0: initial zeros, no wait)
        if (t > 0) {
            if (tid == 0) {
                const int tgt = NBLK * t;
                while (__hip_atomic_load(mycnt, __ATOMIC_RELAXED,
                                         __HIP_MEMORY_SCOPE_AGENT) < tgt)
                    __builtin_amdgcn_s_sleep(1);
            }
            __syncthreads();
        }

        // 3. single-shot wave-local h fetch (7 u64 loads/thread, no re-poll)
        {
            const u64* src = hb + (size_t)(t & 1) * PAIRS;
#pragma unroll
            for (int i = 0; i < 7; ++i) {
                const int j = lane + (i << 6);
                if (j < 400) {
                    const int r  = j / 50;
                    const int pi = j - r * 50;
                    const u64 v = __hip_atomic_load(
                        src + (r * 200 + wave * 50 + pi),
                        __ATOMIC_RELAXED, __HIP_MEMORY_SCOPE_AGENT);
                    float2 f2;
                    f2.x = __uint_as_float((unsigned)v);
                    f2.y = __uint_as_float((unsigned)(v >> 32));
                    *(float2*)&hsm[r][wave * KCH + 2 * pi] = f2;
                }
            }
        }

        // 4. stage x(t+1) into LDS
        if (ldx) {
#pragma unroll
            for (int i = 0; i < 8; ++i)
                if (xgofs[i] >= 0) xsm_f[xlofs[i]] = xr[i];
        }

        // 5. h-FMA (wave-local LDS chunk; within-wave lgkmcnt ordering)
        float acc[RG];
#pragma unroll
        for (int r = 0; r < RG; ++r) acc[r] = accx[r];
#pragma unroll
        for (int k4 = 0; k4 < KCH / 4; ++k4) {
            const float w0 = wreg[k4 * 4 + 0];
            const float w1 = wreg[k4 * 4 + 1];
            const float w2 = wreg[k4 * 4 + 2];
            const float w3 = wreg[k4 * 4 + 3];
#pragma unroll
            for (int r = 0; r < RG; ++r) {
                const float4 hv = *(const float4*)&hsm[r][wave * KCH + k4 * 4];
                acc[r] = fmaf(w0, hv.x, acc[r]);
                acc[r] = fmaf(w1, hv.y, acc[r]);
                acc[r] = fmaf(w2, hv.z, acc[r]);
                acc[r] = fmaf(w3, hv.w, acc[r]);
            }
        }
#pragma unroll
        for (int r = 0; r < RG; ++r) part[wave][r][lane] = acc[r];
        __syncthreads();

        // 6. gate math + state update (tid < 128)
        if (tid < 128) {
            float z[4];
#pragma unroll
            for (int q = 0; q < 4; ++q) {
                const int c = q * HSZ + jjs;
                z[q] = part[0][rr][c] + part[1][rr][c] +
                       part[2][rr][c] + part[3][rr][c] + bq[q];
            }
            const float iv = sigf(z[0]);
            const float fv = sigf(z[1]);
            const float gv = tanhf(z[2]);
            const float ov = sigf(z[3]);
            if (t < mylen) {                  // Keras mask: carry if masked
                cst = fv * cst + iv * gv;
                hst = ov * tanhf(cst);
            }
        }

        // 7. pack h-pairs (shfl) + publish as 8B atomics (even tid < 128)
        const float hnxt = __shfl_down(hst, 1);
        if (tid < 128 && !(tid & 1)) {
            const u64 pk = ((u64)__float_as_uint(hnxt) << 32) |
                           (u64)__float_as_uint(hst);
            __hip_atomic_store(hb + (size_t)(tn & 1) * PAIRS +
                               (rr * 200 + nb * 8 + (jjs >> 1)),
                               pk, __ATOMIC_RELAXED,
                               __HIP_MEMORY_SCOPE_AGENT);
        }
        __syncthreads();   // drain publishes (vmcnt(0)) + part[] reuse guard

        // 8. signal: one relaxed add per block (stores already visible)
        if (tid == 0)
            __hip_atomic_fetch_add(mycnt, 1, __ATOMIC_RELAXED,
                                   __HIP_MEMORY_SCOPE_AGENT);

        // 9. off-critical-path: hs store + x-partial for t+1
        if (tid < 128)
            hs[((size_t)bidx * T_N + t) * H_N + uu] = hst;
        if (ldx) {
#pragma unroll
            for (int r = 0; r < RG; ++r) accx[r] = 0.0f;
#pragma unroll
            for (int k4 = 0; k4 < KXC / 4; ++k4) {
                const float w0 = wxreg[k4 * 4 + 0];
                const float w1 = wxreg[k4 * 4 + 1];
                const float w2 = wxreg[k4 * 4 + 2];
                const float w3 = wxreg[k4 * 4 + 3];
#pragma unroll
                for (int r = 0; r < RG; ++r) {
                    const float4 xv = *(const float4*)&xsm[r][wave * KXC + k4 * 4];
                    accx[r] = fmaf(w0, xv.x, accx[r]);
                    accx[r] = fmaf(w1, xv.y, accx[r]);
                    accx[r] = fmaf(w2, xv.z, accx[r]);
                    accx[r] = fmaf(w3, xv.w, accx[r]);
                }
            }
        }
    }

    // ---- tail: t >= maxlen — h frozen (Keras carry), emit hs rows ----
    if (tid < 128) {
        for (int t = maxlen; t < T_N; ++t)
            hs[((size_t)bidx * T_N + t) * H_N + uu] = hst;
    }
}

// ============================================================
// Dense heads: logits = hs @ Wd + bd over all 28800 rows.
// BM=128, N=73(->80), BK=16.
// ============================================================
__global__ __launch_bounds__(256)
void dense_proj(const float* __restrict__ hs_all,
                const float* __restrict__ Wd_c, const float* __restrict__ bd_c,
                const float* __restrict__ Wd_l, const float* __restrict__ bd_l,
                float* __restrict__ out)
{
    const int L = blockIdx.y;
    const float* hs = hs_all + (size_t)L * HS_SZ;
    const float* Wd = L ? Wd_l : Wd_c;
    const float* bd = L ? bd_l : bd_c;
    float* o = out + (size_t)L * ((size_t)BT * C_N);

    const int m0 = blockIdx.x * 128;
    const int tid = threadIdx.x;

    __shared__ float As[16][132];
    __shared__ float Bs[16][80];

    const int r  = tid >> 1;          // 0..127
    const int kq = (tid & 1) * 8;     // 0/8
    const float* ap_base = hs + (size_t)(m0 + r) * H_N + kq;

    const int ty = tid >> 4, tx = tid & 15;
    float acc[8][5];
#pragma unroll
    for (int i = 0; i < 8; ++i)
#pragma unroll
        for (int j = 0; j < 5; ++j) acc[i][j] = 0.0f;

    for (int k0 = 0; k0 < H_N; k0 += 16) {
        float4 a0 = *(const float4*)(ap_base + k0);
        float4 a1 = *(const float4*)(ap_base + k0 + 4);
        As[kq + 0][r] = a0.x; As[kq + 1][r] = a0.y;
        As[kq + 2][r] = a0.z; As[kq + 3][r] = a0.w;
        As[kq + 4][r] = a1.x; As[kq + 5][r] = a1.y;
        As[kq + 6][r] = a1.z; As[kq + 7][r] = a1.w;
        for (int i = tid; i < 16 * 80; i += 256) {
            int kk = i / 80, c = i - kk * 80;
            Bs[kk][c] = (c < C_N) ? Wd[(size_t)(k0 + kk) * C_N + c] : 0.0f;
        }
        __syncthreads();
#pragma unroll
        for (int kk = 0; kk < 16; ++kk) {
            float a[8], bb[5];
            *(float4*)&a[0] = *(const float4*)&As[kk][ty * 8];
            *(float4*)&a[4] = *(const float4*)&As[kk][ty * 8 + 4];
#pragma unroll
            for (int j = 0; j < 5; ++j) bb[j] = Bs[kk][tx * 5 + j];
#pragma unroll
            for (int i = 0; i < 8; ++i)
#pragma unroll
                for (int j = 0; j < 5; ++j)
                    acc[i][j] = fmaf(a[i], bb[j], acc[i][j]);
        }
        __syncthreads();
    }

#pragma unroll
    for (int i = 0; i < 8; ++i) {
        const int m = m0 + ty * 8 + i;
#pragma unroll
        for (int j = 0; j < 5; ++j) {
            const int c = tx * 5 + j;
            if (c < C_N)
                o[(size_t)m * C_N + c] = acc[i][j] + bd[c];
        }
    }
}

// ============================================================
// max |a - b|  -> scalar (atomicMax on int bits, vals >= 0)
// ============================================================
__global__ void maxdiff_k(const float* __restrict__ a,
                          const float* __restrict__ b,
                          int* __restrict__ outbits, size_t n)
{
    size_t i0 = (size_t)blockIdx.x * blockDim.x + threadIdx.x;
    float m = 0.0f;
    for (size_t i = i0; i < n; i += (size_t)gridDim.x * blockDim.x) {
        float d = fabsf(a[i] - b[i]);
        m = d > m ? d : m;
    }
#pragma unroll
    for (int off = 32; off > 0; off >>= 1) {
        float o = __shfl_down(m, off, 64);
        m = o > m ? o : m;
    }
    __shared__ float sm[4];
    if ((threadIdx.x & 63) == 0) sm[threadIdx.x >> 6] = m;
    __syncthreads();
    if (threadIdx.x == 0) {
        float mm = sm[0];
#pragma unroll
        for (int w = 1; w < 4; ++w) mm = sm[w] > mm ? sm[w] : mm;
        atomicMax(outbits, __float_as_int(mm));
    }
}

// ============================================================
extern "C" void kernel_launch(void* const* d_in, const int* in_sizes, int n_in,
                              void* d_out, int out_size, void* d_ws, size_t ws_size,
                              hipStream_t stream)
{
    const float* x    = (const float*)d_in[0];
    const int*   slen = (const int*)  d_in[1];
    const float* Wx_c = (const float*)d_in[2];
    const float* Wh_c = (const float*)d_in[3];
    const float* b_c  = (const float*)d_in[4];
    const float* Wx_l = (const float*)d_in[5];
    const float* Wh_l = (const float*)d_in[6];
    const float* b_l  = (const float*)d_in[7];
    const float* Wd_c = (const float*)d_in[8];
    const float* bd_c = (const float*)d_in[9];
    const float* Wd_l = (const float*)d_in[10];
    const float* bd_l = (const float*)d_in[11];

    float* ws    = (float*)d_ws;
    float* hsbuf = ws + HS_OFF;
    u64*   hb64  = (u64*)(ws + HB_OFF);
    int*   cnt   = (int*)(ws + CNT_OFF);
    float* out   = (float*)d_out;

    // zero h-broadcast buffers (zeros == h(0)=0 initial state) + counters
    // (contiguous after hb64) + output scalar slot
    hipMemsetAsync(hb64, 0, HB_U64 * sizeof(u64) + CNT_I * sizeof(int),
                   stream);
    hipMemsetAsync(out + 2 * (size_t)BT * C_N, 0, sizeof(float), stream);

    // 1) full recurrence, both LSTMs, x@Wx fused (single dispatch)
    lstm_rec<<<dim3(2 * NGRP * NBLK), dim3(256), 0, stream>>>(
        Wh_c, Wh_l, Wx_c, Wx_l, b_c, b_l, slen, x, hsbuf, hb64, cnt);

    // 2) dense heads (all rows at once)
    {
        dim3 grid(BT / 128, 2);   // (225, 2)
        dense_proj<<<grid, 256, 0, stream>>>(hsbuf, Wd_c, bd_c, Wd_l, bd_l,
                                             out);
    }

    // 3) max |logits_c - logits_l|
    maxdiff_k<<<dim3(1024), 256, 0, stream>>>(
        out, out + (size_t)BT * C_N, (int*)(out + 2 * (size_t)BT * C_N),
        (size_t)BT * C_N);
}